// Round 1
// baseline (236.456 us; speedup 1.0000x reference)
//
#include <hip/hip_runtime.h>
#include <hip/hip_cooperative_groups.h>
#include <cstddef>

namespace cg = cooperative_groups;

#define BATCH 64
#define HH 512
#define WW 512
#define NROWS (BATCH * HH)          // 32768 flattened (b,i) rows
#define RVAL (1.0f / 512.0f)        // r = c = 1/512, exact in fp32
#define EPS_ 1e-6f
#define MAXIT 100
#define NBLK 256
#define NTHR 512

// Sinkhorn with factored scaling: P = diag(u) * exp(-M) * diag(v).
// Phase A: u_i = r / sum_j exp(-M_ij) v_j          (wave-per-row dot)
// Phase B: t_j = sum_i u_i exp(-M_ij); beta = v*t; global convergence flag;
//          vnext = c / t
// Early exit when all |beta - c| <= eps (matches torch "break before col-norm").
__global__ __launch_bounds__(NTHR, 1)
void sinkhorn_k(const float* __restrict__ M, float* __restrict__ P,
                float* __restrict__ scratch) {
    float* u   = scratch;                 // NROWS
    float* vb0 = scratch + NROWS;         // NROWS
    float* vb1 = scratch + 2 * NROWS;     // NROWS
    int*   flg = (int*)(scratch + 3 * NROWS);  // MAXIT ints

    const int tid  = threadIdx.x;
    const int bid  = blockIdx.x;
    const int gtid = bid * NTHR + tid;
    const int lane = tid & 63;
    const int wave = tid >> 6;

    cg::grid_group grid = cg::this_grid();

    // init scratch every call (deterministic, no cross-call state)
    if (gtid < NROWS) vb0[gtid] = 1.0f;
    if (gtid < MAXIT) flg[gtid] = 0;
    grid.sync();

    float* vcur = vb0;
    float* vnxt = vb1;

    __shared__ float4 red[NTHR];   // 8 KB phase-B reduction buffer

    for (int it = 0; it < MAXIT; ++it) {
        // ---- Phase A: row sums -> u ----
        {
            const int rbase = bid * 128 + wave * 16;
            for (int rr = 0; rr < 16; ++rr) {
                const int row = rbase + rr;
                const int b   = row >> 9;
                const float4* Mr = (const float4*)(M + (size_t)row * WW);
                const float4* vr = (const float4*)(vcur + (b << 9));
                float4 m0 = Mr[lane], m1 = Mr[lane + 64];
                float4 v0 = vr[lane], v1 = vr[lane + 64];
                float s = __expf(-m0.x) * v0.x + __expf(-m0.y) * v0.y
                        + __expf(-m0.z) * v0.z + __expf(-m0.w) * v0.w
                        + __expf(-m1.x) * v1.x + __expf(-m1.y) * v1.y
                        + __expf(-m1.z) * v1.z + __expf(-m1.w) * v1.w;
#pragma unroll
                for (int off = 32; off >= 1; off >>= 1)
                    s += __shfl_xor(s, off, 64);
                if (lane == 0) u[row] = RVAL / s;
            }
        }
        grid.sync();

        // ---- Phase B: col sums -> beta check, vnext ----
        bool viol = false;
        {
            const int b     = bid >> 2;          // 4 blocks per batch
            const int j0    = (bid & 3) * 128;   // 128 cols per block
            const int fc    = tid & 31;          // float4-column index
            const int chunk = tid >> 5;          // 16 row-chunks of 32
            const float* Mb = M + (size_t)b * HH * WW;
            const float* ub = u + (b << 9);
            float4 s4 = make_float4(0.f, 0.f, 0.f, 0.f);
            const float* mp = Mb + (size_t)(chunk * 32) * WW + j0 + fc * 4;
            const int ib = chunk * 32;
#pragma unroll 4
            for (int i = 0; i < 32; ++i) {
                float ui = ub[ib + i];
                float4 m = *(const float4*)(mp + (size_t)i * WW);
                s4.x += ui * __expf(-m.x);
                s4.y += ui * __expf(-m.y);
                s4.z += ui * __expf(-m.z);
                s4.w += ui * __expf(-m.w);
            }
            red[tid] = s4;
            __syncthreads();
            if (tid < 32) {
                float4 t = red[tid];
#pragma unroll
                for (int k = 1; k < 16; ++k) {
                    float4 rk = red[tid + 32 * k];
                    t.x += rk.x; t.y += rk.y; t.z += rk.z; t.w += rk.w;
                }
                const int j = j0 + tid * 4;
                float4 vc = *(const float4*)(vcur + (b << 9) + j);
                float bx = vc.x * t.x, by = vc.y * t.y;
                float bz = vc.z * t.z, bw = vc.w * t.w;
                viol = (fabsf(bx - RVAL) > EPS_) | (fabsf(by - RVAL) > EPS_)
                     | (fabsf(bz - RVAL) > EPS_) | (fabsf(bw - RVAL) > EPS_);
                float4 vn = make_float4(RVAL / t.x, RVAL / t.y,
                                        RVAL / t.z, RVAL / t.w);
                *(float4*)(vnxt + (b << 9) + j) = vn;
            }
            if (__any(viol)) {
                if (tid == 0) atomicOr(&flg[it], 1);
            }
        }
        grid.sync();

        int nc = __hip_atomic_load(&flg[it], __ATOMIC_RELAXED,
                                   __HIP_MEMORY_SCOPE_AGENT);
        if (!nc) break;                 // converged: keep row-normalized state
        float* t = vcur; vcur = vnxt; vnxt = t;   // col-normalize accepted
    }

    // ---- Final: P_ij = u_i * exp(-M_ij) * v_j ----
    // Stage u,v to LDS, then grid-sync so scratch (possibly in d_out tail)
    // may be safely overwritten by P stores.
    __shared__ float s_u[128];
    __shared__ float s_v[WW];
    const int row0 = bid * 128;
    const int bb   = row0 >> 9;
    if (tid < 128) s_u[tid] = u[row0 + tid];
    if (tid < WW)  s_v[tid] = vcur[(bb << 9) + tid];
    __syncthreads();
    grid.sync();

    const float4* sv4 = (const float4*)s_v;
    for (int rr = wave; rr < 128; rr += 8) {
        const int row = row0 + rr;
        const float ui = s_u[rr];
        const float4* Mr = (const float4*)(M + (size_t)row * WW);
        float4* Pr = (float4*)(P + (size_t)row * WW);
        float4 m0 = Mr[lane], m1 = Mr[lane + 64];
        float4 v0 = sv4[lane], v1 = sv4[lane + 64];
        float4 p0, p1;
        p0.x = ui * __expf(-m0.x) * v0.x;
        p0.y = ui * __expf(-m0.y) * v0.y;
        p0.z = ui * __expf(-m0.z) * v0.z;
        p0.w = ui * __expf(-m0.w) * v0.w;
        p1.x = ui * __expf(-m1.x) * v1.x;
        p1.y = ui * __expf(-m1.y) * v1.y;
        p1.z = ui * __expf(-m1.z) * v1.z;
        p1.w = ui * __expf(-m1.w) * v1.w;
        Pr[lane]      = p0;
        Pr[lane + 64] = p1;
    }
}

extern "C" void kernel_launch(void* const* d_in, const int* in_sizes, int n_in,
                              void* d_out, int out_size, void* d_ws, size_t ws_size,
                              hipStream_t stream) {
    const float* M = (const float*)d_in[0];
    float* P = (float*)d_out;

    // scratch: u + v0 + v1 + flags
    const size_t SCR = (size_t)(3 * NROWS + 256) * sizeof(float);
    float* scratch;
    if (ws_size >= SCR) {
        scratch = (float*)d_ws;
    } else {
        // fall back to the tail of d_out; final phase stages u,v into LDS
        // and grid-syncs before P stores overwrite this region.
        scratch = (float*)((char*)d_out + (size_t)out_size * sizeof(float) - SCR);
    }

    void* args[] = { (void*)&M, (void*)&P, (void*)&scratch };
    hipLaunchCooperativeKernel((const void*)sinkhorn_k, dim3(NBLK), dim3(NTHR),
                               args, 0, stream);
}